// Round 1
// baseline (423.653 us; speedup 1.0000x reference)
//
#include <hip/hip_runtime.h>
#include <hip/hip_bf16.h>

// Problem: B=16, N=2048, F=128, HID=32, FC=512, C=10
// Key simplification: softmax over size-1 cluster axis => S == 1, so
//   Xp[b,h] = sum_n relu( (A @ (X@W1))[b,n,h] + b1[h] )
// and the second einsum (A@H) + Ws are dead code. Only one 268 MB pass over A.

#define B_   16
#define N_   2048
#define F_   128
#define HID_ 32
#define FC_  512
#define C_   10

typedef __bf16 bf16x8 __attribute__((ext_vector_type(8)));
typedef float  f32x4  __attribute__((ext_vector_type(4)));
typedef float  floatx4 __attribute__((ext_vector_type(4)));

// ---------------------------------------------------------------------------
// Kernel 1: XWT[b][h][m] = (X[b] @ W1)[m][h] in bf16 (transposed layout so the
// big kernel's B-fragments are contiguous ds/global reads). Also zeros Xp.
// MFMA roles: A-op = W1^T (M=HID=32 rows, K=F=128), B-op = X^T (K=f, N=m cols)
// ---------------------------------------------------------------------------
__global__ __launch_bounds__(256) void k1_xw(
    const float* __restrict__ X, const float* __restrict__ W1,
    __bf16* __restrict__ XWT, float* __restrict__ Xp)
{
    const int tid = threadIdx.x;
    if (blockIdx.x == 0) {
        for (int i = tid; i < B_ * HID_; i += 256) Xp[i] = 0.f;
    }
    const int b   = blockIdx.x >> 4;   // 256 blocks: 16 per batch
    const int seg = blockIdx.x & 15;   // 128 m-columns per block
    const int w    = tid >> 6;
    const int lane = tid & 63;
    const int r = lane & 15, q = lane >> 4;

    // A-operand fragments: lane holds W1T[h = r(+16t)][f = ks*32 + q*8 + j]
    bf16x8 wf[2][4];
    #pragma unroll
    for (int t = 0; t < 2; ++t) {
        const int h = r + 16 * t;
        #pragma unroll
        for (int ks = 0; ks < 4; ++ks) {
            bf16x8 v;
            #pragma unroll
            for (int j = 0; j < 8; ++j) {
                const int f = ks * 32 + q * 8 + j;
                v[j] = (__bf16)W1[f * HID_ + h];
            }
            wf[t][ks] = v;
        }
    }

    #pragma unroll
    for (int i = 0; i < 2; ++i) {
        const int m0 = seg * 128 + w * 16 + i * 64;
        const int m  = m0 + r;  // B-op col for loads AND D col for stores
        const floatx4* xrow = (const floatx4*)(X + ((size_t)(b * N_ + m)) * F_);
        f32x4 acc0 = {0.f, 0.f, 0.f, 0.f};
        f32x4 acc1 = {0.f, 0.f, 0.f, 0.f};
        #pragma unroll
        for (int ks = 0; ks < 4; ++ks) {
            floatx4 x0 = xrow[ks * 8 + q * 2];
            floatx4 x1 = xrow[ks * 8 + q * 2 + 1];
            bf16x8 bf;
            bf[0] = (__bf16)x0[0]; bf[1] = (__bf16)x0[1];
            bf[2] = (__bf16)x0[2]; bf[3] = (__bf16)x0[3];
            bf[4] = (__bf16)x1[0]; bf[5] = (__bf16)x1[1];
            bf[6] = (__bf16)x1[2]; bf[7] = (__bf16)x1[3];
            acc0 = __builtin_amdgcn_mfma_f32_16x16x32_bf16(wf[0][ks], bf, acc0, 0, 0, 0);
            acc1 = __builtin_amdgcn_mfma_f32_16x16x32_bf16(wf[1][ks], bf, acc1, 0, 0, 0);
        }
        // D layout: col(=m) = lane&15, row(=h within tile) = q*4 + reg
        #pragma unroll
        for (int reg = 0; reg < 4; ++reg) {
            const int h0 = q * 4 + reg;
            XWT[((size_t)(b * HID_ + h0)) * N_ + m]      = (__bf16)acc0[reg];
            XWT[((size_t)(b * HID_ + h0 + 16)) * N_ + m] = (__bf16)acc1[reg];
        }
    }
}

// ---------------------------------------------------------------------------
// Kernel 2 (the 268 MB pass): per wave, 16 rows of A x full K=2048.
//   acc[16x32] = A_rows @ XW   (bf16 MFMA, fp32 accum)
// Epilogue fuses  + b1, relu, sum over the 16 rows -> 32 partials -> atomicAdd.
// A-frag loaded directly from global fp32 (32 B/lane contiguous) + cvt to bf16.
// ---------------------------------------------------------------------------
__global__ __launch_bounds__(128) void k2_axw(
    const float* __restrict__ A, const __bf16* __restrict__ XWT,
    const float* __restrict__ b1, float* __restrict__ Xp)
{
    const int tid = threadIdx.x;
    const int b       = blockIdx.x >> 6;          // 1024 blocks: 64 per batch
    const int rowBase = (blockIdx.x & 63) * 32;   // 2 waves x 16 rows
    const int w    = tid >> 6;
    const int lane = tid & 63;
    const int r = lane & 15, q = lane >> 4;
    const int row = rowBase + w * 16 + r;         // A-frag source row for this lane

    const floatx4* arow = (const floatx4*)(A + ((size_t)b * N_ + row) * (size_t)N_);
    const bf16x8* bp0 = (const bf16x8*)(XWT + ((size_t)(b * HID_ + r)) * N_);
    const bf16x8* bp1 = (const bf16x8*)(XWT + ((size_t)(b * HID_ + r + 16)) * N_);

    f32x4 acc0 = {0.f, 0.f, 0.f, 0.f};
    f32x4 acc1 = {0.f, 0.f, 0.f, 0.f};

    #pragma unroll 4
    for (int ks = 0; ks < N_ / 32; ++ks) {
        floatx4 a0 = arow[ks * 8 + q * 2];        // lane covers 32 contiguous B
        floatx4 a1 = arow[ks * 8 + q * 2 + 1];
        bf16x8 af;
        af[0] = (__bf16)a0[0]; af[1] = (__bf16)a0[1];
        af[2] = (__bf16)a0[2]; af[3] = (__bf16)a0[3];
        af[4] = (__bf16)a1[0]; af[5] = (__bf16)a1[1];
        af[6] = (__bf16)a1[2]; af[7] = (__bf16)a1[3];
        bf16x8 bf0 = bp0[ks * 4 + q];             // L2-resident (2 MB total)
        bf16x8 bf1 = bp1[ks * 4 + q];
        acc0 = __builtin_amdgcn_mfma_f32_16x16x32_bf16(af, bf0, acc0, 0, 0, 0);
        acc1 = __builtin_amdgcn_mfma_f32_16x16x32_bf16(af, bf1, acc1, 0, 0, 0);
    }

    // Epilogue: D col(h) = r(+16), rows = q*4+reg. relu AFTER full-K bias add,
    // then sum over this wave's 16 rows (4 regs + quad reduction).
    const float bias0 = b1[r], bias1 = b1[r + 16];
    float s0 = 0.f, s1 = 0.f;
    #pragma unroll
    for (int reg = 0; reg < 4; ++reg) {
        s0 += fmaxf(acc0[reg] + bias0, 0.f);
        s1 += fmaxf(acc1[reg] + bias1, 0.f);
    }
    s0 += __shfl_xor(s0, 16); s0 += __shfl_xor(s0, 32);
    s1 += __shfl_xor(s1, 16); s1 += __shfl_xor(s1, 32);

    __shared__ float sdata[2][HID_];
    if (lane < 16) { sdata[w][r] = s0; sdata[w][r + 16] = s1; }
    __syncthreads();
    if (tid < HID_) {
        atomicAdd(&Xp[b * HID_ + tid], sdata[0][tid] + sdata[1][tid]);
    }
}

// ---------------------------------------------------------------------------
// Kernel 3: dense head per batch: h = relu(Xp@Wd+bd); out = softmax(h@Wc+bc)
// ---------------------------------------------------------------------------
__global__ __launch_bounds__(256) void k3_head(
    const float* __restrict__ Xp, const float* __restrict__ Wd,
    const float* __restrict__ bd, const float* __restrict__ Wc,
    const float* __restrict__ bc, float* __restrict__ out)
{
    __shared__ float xp[HID_];
    __shared__ float hbuf[FC_];
    __shared__ float logits[C_];
    const int b = blockIdx.x;
    const int t = threadIdx.x;

    if (t < HID_) xp[t] = Xp[b * HID_ + t];
    __syncthreads();

    for (int f = t; f < FC_; f += 256) {
        float acc = bd[f];
        #pragma unroll
        for (int j = 0; j < HID_; ++j) acc += xp[j] * Wd[j * FC_ + f];
        hbuf[f] = fmaxf(acc, 0.f);
    }
    __syncthreads();

    if (t < 16 * C_) {
        const int c = t >> 4, l = t & 15;   // 16 lanes per class, wave-aligned
        float acc = 0.f;
        for (int f = l; f < FC_; f += 16) acc += hbuf[f] * Wc[f * C_ + c];
        acc += __shfl_xor(acc, 8, 16);
        acc += __shfl_xor(acc, 4, 16);
        acc += __shfl_xor(acc, 2, 16);
        acc += __shfl_xor(acc, 1, 16);
        if (l == 0) logits[c] = acc + bc[c];
    }
    __syncthreads();

    if (t == 0) {
        float mx = logits[0];
        #pragma unroll
        for (int c = 1; c < C_; ++c) mx = fmaxf(mx, logits[c]);
        float e[C_]; float sum = 0.f;
        #pragma unroll
        for (int c = 0; c < C_; ++c) { e[c] = expf(logits[c] - mx); sum += e[c]; }
        const float inv = 1.f / sum;
        #pragma unroll
        for (int c = 0; c < C_; ++c) out[b * C_ + c] = e[c] * inv;
    }
}

// ---------------------------------------------------------------------------
extern "C" void kernel_launch(void* const* d_in, const int* in_sizes, int n_in,
                              void* d_out, int out_size, void* d_ws, size_t ws_size,
                              hipStream_t stream) {
    const float* filtre = (const float*)d_in[0];
    const float* X      = (const float*)d_in[1];
    // d_in[2] node_indicator: unused by the reference
    const float* W1     = (const float*)d_in[3];
    const float* b1     = (const float*)d_in[4];
    // d_in[5] Ws: dead code (softmax over size-1 axis == 1)
    const float* Wd     = (const float*)d_in[6];
    const float* bd     = (const float*)d_in[7];
    const float* Wc     = (const float*)d_in[8];
    const float* bc     = (const float*)d_in[9];
    float* out = (float*)d_out;

    __bf16* XWT = (__bf16*)d_ws;                                   // 2 MB
    float*  Xp  = (float*)((char*)d_ws + (size_t)B_ * HID_ * N_ * sizeof(__bf16));

    k1_xw <<<256,  256, 0, stream>>>(X, W1, XWT, Xp);
    k2_axw<<<1024, 128, 0, stream>>>(filtre, XWT, b1, Xp);
    k3_head<<<B_,  256, 0, stream>>>(Xp, Wd, bd, Wc, bc, out);
}

// Round 2
// 416.385 us; speedup vs baseline: 1.0175x; 1.0175x over previous
//
#include <hip/hip_runtime.h>
#include <hip/hip_bf16.h>

// Problem: B=16, N=2048, F=128, HID=32, FC=512, C=10
// Key simplification: softmax over size-1 cluster axis => S == 1, so
//   Xp[b,h] = sum_n relu( (A @ (X@W1))[b,n,h] + b1[h] )
// and the second einsum (A@H) + Ws are dead code. One 268 MB pass over A.
// k2 v2: async global_load_lds staging, per-wave-private LDS ring (no barrier
// in K-loop), XOR-swizzled DMA source so LDS b128 reads are conflict-free.

#define B_   16
#define N_   2048
#define F_   128
#define HID_ 32
#define FC_  512
#define C_   10

typedef __bf16 bf16x8 __attribute__((ext_vector_type(8)));
typedef float  f32x4  __attribute__((ext_vector_type(4)));
typedef float  floatx4 __attribute__((ext_vector_type(4)));

typedef const __attribute__((address_space(1))) void* as1_cvp;
typedef __attribute__((address_space(3))) void*       as3_vp;

__device__ static __forceinline__ void dma16(void* lds_uniform, const void* g) {
    __builtin_amdgcn_global_load_lds((as1_cvp)g, (as3_vp)lds_uniform, 16, 0, 0);
}

// ---------------------------------------------------------------------------
// Kernel 1: XWT[b][h][m] = (X[b] @ W1)[m][h] in bf16. Also zeros Xp.
// (unchanged from round 1 — verified correct)
// ---------------------------------------------------------------------------
__global__ __launch_bounds__(256) void k1_xw(
    const float* __restrict__ X, const float* __restrict__ W1,
    __bf16* __restrict__ XWT, float* __restrict__ Xp)
{
    const int tid = threadIdx.x;
    if (blockIdx.x == 0) {
        for (int i = tid; i < B_ * HID_; i += 256) Xp[i] = 0.f;
    }
    const int b   = blockIdx.x >> 4;
    const int seg = blockIdx.x & 15;
    const int w    = tid >> 6;
    const int lane = tid & 63;
    const int r = lane & 15, q = lane >> 4;

    bf16x8 wf[2][4];
    #pragma unroll
    for (int t = 0; t < 2; ++t) {
        const int h = r + 16 * t;
        #pragma unroll
        for (int ks = 0; ks < 4; ++ks) {
            bf16x8 v;
            #pragma unroll
            for (int j = 0; j < 8; ++j) {
                const int f = ks * 32 + q * 8 + j;
                v[j] = (__bf16)W1[f * HID_ + h];
            }
            wf[t][ks] = v;
        }
    }

    #pragma unroll
    for (int i = 0; i < 2; ++i) {
        const int m0 = seg * 128 + w * 16 + i * 64;
        const int m  = m0 + r;
        const floatx4* xrow = (const floatx4*)(X + ((size_t)(b * N_ + m)) * F_);
        f32x4 acc0 = {0.f, 0.f, 0.f, 0.f};
        f32x4 acc1 = {0.f, 0.f, 0.f, 0.f};
        #pragma unroll
        for (int ks = 0; ks < 4; ++ks) {
            floatx4 x0 = xrow[ks * 8 + q * 2];
            floatx4 x1 = xrow[ks * 8 + q * 2 + 1];
            bf16x8 bf;
            bf[0] = (__bf16)x0[0]; bf[1] = (__bf16)x0[1];
            bf[2] = (__bf16)x0[2]; bf[3] = (__bf16)x0[3];
            bf[4] = (__bf16)x1[0]; bf[5] = (__bf16)x1[1];
            bf[6] = (__bf16)x1[2]; bf[7] = (__bf16)x1[3];
            acc0 = __builtin_amdgcn_mfma_f32_16x16x32_bf16(wf[0][ks], bf, acc0, 0, 0, 0);
            acc1 = __builtin_amdgcn_mfma_f32_16x16x32_bf16(wf[1][ks], bf, acc1, 0, 0, 0);
        }
        #pragma unroll
        for (int reg = 0; reg < 4; ++reg) {
            const int h0 = q * 4 + reg;
            XWT[((size_t)(b * HID_ + h0)) * N_ + m]      = (__bf16)acc0[reg];
            XWT[((size_t)(b * HID_ + h0 + 16)) * N_ + m] = (__bf16)acc1[reg];
        }
    }
}

// ---------------------------------------------------------------------------
// Kernel 2 (the 268 MB pass), v2: DMA-staged A, per-wave-private LDS ring.
// Grid 512 blocks x 256 thr. Block = 64 rows full-K; wave = 16 rows.
// K-chunks of 64 fp32 cols (4 KB/wave/chunk, 4 DMA instrs), NBUF=4 ring.
// Pipeline: stage(c+2); waitcnt(vmcnt<=4); compute(c)  -> chunk c landed one
// iteration early; waves stall with 4-8 KB posted => ~32-64 KB/CU in flight.
// LDS 16B-chunk slot s in row r holds global chunk s^(r&7) (bank de-conflict).
// ---------------------------------------------------------------------------
__global__ __launch_bounds__(256, 2) void k2_axw(
    const float* __restrict__ A, const __bf16* __restrict__ XWT,
    const float* __restrict__ b1, float* __restrict__ Xp)
{
    __shared__ __align__(16) float abuf[4][4][16 * 64]; // [buf][wave][row*64+chunk*4] 64 KB
    __shared__ float sdata[4][HID_];

    const int tid  = threadIdx.x;
    const int w    = tid >> 6;
    const int lane = tid & 63;
    const int r = lane & 15, q = lane >> 4;
    const int rs = r & 7;

    const int b       = blockIdx.x >> 5;          // 512 blocks: 32 per batch
    const int rowBase = (blockIdx.x & 31) * 64;   // 4 waves x 16 rows
    const int row0    = rowBase + w * 16;

    const int rl = lane >> 4;     // row sub-index within a DMA instr (0..3)
    const int ch = lane & 15;     // 16B chunk slot within LDS row

    const bf16x8* bp0 = (const bf16x8*)(XWT + ((size_t)(b * HID_ + r)) * N_);
    const bf16x8* bp1 = (const bf16x8*)(XWT + ((size_t)(b * HID_ + r + 16)) * N_);

    f32x4 acc0 = {0.f, 0.f, 0.f, 0.f};
    f32x4 acc1 = {0.f, 0.f, 0.f, 0.f};

    auto stage = [&](int c) {
        const int t = c & 3;
        #pragma unroll
        for (int j = 0; j < 4; ++j) {
            const int rlocal = j * 4 + rl;                       // 0..15
            const int gchunk = ch ^ (rlocal & 7);                // swizzled source
            const size_t gelem = ((size_t)(b * N_ + row0 + rlocal)) * N_
                               + (size_t)c * 64 + (size_t)(gchunk * 4);
            dma16((void*)&abuf[t][w][j * 256], (const void*)(A + gelem));
        }
    };

    auto compute = [&](int c) {
        const int t = c & 3;
        const float* aw = &abuf[t][w][0];
        #pragma unroll
        for (int kl = 0; kl < 2; ++kl) {
            const int s0 = (kl * 8 + q * 2) ^ rs;                // G0 even -> s1 = s0^1
            const floatx4 u0 = *(const floatx4*)(aw + r * 64 + s0 * 4);
            const floatx4 u1 = *(const floatx4*)(aw + r * 64 + (s0 ^ 1) * 4);
            bf16x8 af;
            af[0] = (__bf16)u0[0]; af[1] = (__bf16)u0[1];
            af[2] = (__bf16)u0[2]; af[3] = (__bf16)u0[3];
            af[4] = (__bf16)u1[0]; af[5] = (__bf16)u1[1];
            af[6] = (__bf16)u1[2]; af[7] = (__bf16)u1[3];
            const int ksg = c * 2 + kl;
            bf16x8 bf0 = bp0[ksg * 4 + q];
            bf16x8 bf1 = bp1[ksg * 4 + q];
            acc0 = __builtin_amdgcn_mfma_f32_16x16x32_bf16(af, bf0, acc0, 0, 0, 0);
            acc1 = __builtin_amdgcn_mfma_f32_16x16x32_bf16(af, bf1, acc1, 0, 0, 0);
        }
    };

    stage(0);
    stage(1);
    for (int c = 0; c < 32; ++c) {
        if (c + 2 < 32) stage(c + 2);
        // s_waitcnt imm: vmcnt[3:0], expcnt[6:4]=7 (ignore), lgkmcnt[11:8]=15 (ignore)
        if (c + 1 < 32) __builtin_amdgcn_s_waitcnt(0x0F74);  // vmcnt(4): chunk c+1 landed
        else            __builtin_amdgcn_s_waitcnt(0x0F70);  // vmcnt(0): drain tail
        compute(c);
    }

    // Epilogue: D col(h)=r(+16), rows=q*4+reg. bias+relu after full K, then
    // sum over this wave's 16 rows; cross-wave combine in LDS; one atomic set.
    const float bias0 = b1[r], bias1 = b1[r + 16];
    float s0 = 0.f, s1 = 0.f;
    #pragma unroll
    for (int reg = 0; reg < 4; ++reg) {
        s0 += fmaxf(acc0[reg] + bias0, 0.f);
        s1 += fmaxf(acc1[reg] + bias1, 0.f);
    }
    s0 += __shfl_xor(s0, 16); s0 += __shfl_xor(s0, 32);
    s1 += __shfl_xor(s1, 16); s1 += __shfl_xor(s1, 32);

    if (lane < 16) { sdata[w][r] = s0; sdata[w][r + 16] = s1; }
    __syncthreads();
    if (tid < HID_) {
        atomicAdd(&Xp[b * HID_ + tid],
                  sdata[0][tid] + sdata[1][tid] + sdata[2][tid] + sdata[3][tid]);
    }
}

// ---------------------------------------------------------------------------
// Kernel 3: dense head per batch (unchanged — verified correct)
// ---------------------------------------------------------------------------
__global__ __launch_bounds__(256) void k3_head(
    const float* __restrict__ Xp, const float* __restrict__ Wd,
    const float* __restrict__ bd, const float* __restrict__ Wc,
    const float* __restrict__ bc, float* __restrict__ out)
{
    __shared__ float xp[HID_];
    __shared__ float hbuf[FC_];
    __shared__ float logits[C_];
    const int b = blockIdx.x;
    const int t = threadIdx.x;

    if (t < HID_) xp[t] = Xp[b * HID_ + t];
    __syncthreads();

    for (int f = t; f < FC_; f += 256) {
        float acc = bd[f];
        #pragma unroll
        for (int j = 0; j < HID_; ++j) acc += xp[j] * Wd[j * FC_ + f];
        hbuf[f] = fmaxf(acc, 0.f);
    }
    __syncthreads();

    if (t < 16 * C_) {
        const int c = t >> 4, l = t & 15;
        float acc = 0.f;
        for (int f = l; f < FC_; f += 16) acc += hbuf[f] * Wc[f * C_ + c];
        acc += __shfl_xor(acc, 8, 16);
        acc += __shfl_xor(acc, 4, 16);
        acc += __shfl_xor(acc, 2, 16);
        acc += __shfl_xor(acc, 1, 16);
        if (l == 0) logits[c] = acc + bc[c];
    }
    __syncthreads();

    if (t == 0) {
        float mx = logits[0];
        #pragma unroll
        for (int c = 1; c < C_; ++c) mx = fmaxf(mx, logits[c]);
        float e[C_]; float sum = 0.f;
        #pragma unroll
        for (int c = 0; c < C_; ++c) { e[c] = expf(logits[c] - mx); sum += e[c]; }
        const float inv = 1.f / sum;
        #pragma unroll
        for (int c = 0; c < C_; ++c) out[b * C_ + c] = e[c] * inv;
    }
}

// ---------------------------------------------------------------------------
extern "C" void kernel_launch(void* const* d_in, const int* in_sizes, int n_in,
                              void* d_out, int out_size, void* d_ws, size_t ws_size,
                              hipStream_t stream) {
    const float* filtre = (const float*)d_in[0];
    const float* X      = (const float*)d_in[1];
    // d_in[2] node_indicator: unused by the reference
    const float* W1     = (const float*)d_in[3];
    const float* b1     = (const float*)d_in[4];
    // d_in[5] Ws: dead code (softmax over size-1 axis == 1)
    const float* Wd     = (const float*)d_in[6];
    const float* bd     = (const float*)d_in[7];
    const float* Wc     = (const float*)d_in[8];
    const float* bc     = (const float*)d_in[9];
    float* out = (float*)d_out;

    __bf16* XWT = (__bf16*)d_ws;                                   // 2 MB
    float*  Xp  = (float*)((char*)d_ws + (size_t)B_ * HID_ * N_ * sizeof(__bf16));

    k1_xw <<<256, 256, 0, stream>>>(X, W1, XWT, Xp);
    k2_axw<<<512, 256, 0, stream>>>(filtre, XWT, b1, Xp);
    k3_head<<<B_,  256, 0, stream>>>(Xp, Wd, bd, Wc, bc, out);
}